// Round 1
// baseline (601.624 us; speedup 1.0000x reference)
//
#include <hip/hip_runtime.h>

// Output layout (floats): x_top[262144] | y_min[16384] | z_val[393216] | z_idx[393216]
#define OUT_X  0
#define OUT_Y  262144
#define OUT_ZV 278528
#define OUT_ZI 671744

// ---------------- x: top-4 over rows of 1024 ----------------

__device__ __forceinline__ void bub4(float &a0, float &a1, float &a2, float &a3, float v) {
    float r;
    r = fminf(a0, v); a0 = fmaxf(a0, v); v = r;
    r = fminf(a1, v); a1 = fmaxf(a1, v); v = r;
    r = fminf(a2, v); a2 = fmaxf(a2, v); v = r;
    a3 = fmaxf(a3, v);
}

__global__ __launch_bounds__(256) void topk_x_kernel(const float* __restrict__ x,
                                                     float* __restrict__ out) {
    const int lane = threadIdx.x & 63;
    const int row  = blockIdx.x * 4 + (threadIdx.x >> 6);   // 65536 rows
    const float4* r4 = (const float4*)(x + (size_t)row * 1024);

    float a0 = -3.402823466e38f, a1 = a0, a2 = a0, a3 = a0;
    #pragma unroll
    for (int c = 0; c < 4; ++c) {
        float4 v = r4[lane + 64 * c];
        bub4(a0, a1, a2, a3, v.x);
        bub4(a0, a1, a2, a3, v.y);
        bub4(a0, a1, a2, a3, v.z);
        bub4(a0, a1, a2, a3, v.w);
    }

    // butterfly merge of sorted-desc 4-lists
    #pragma unroll
    for (int m = 1; m < 64; m <<= 1) {
        float b0 = __shfl_xor(a0, m, 64);
        float b1 = __shfl_xor(a1, m, 64);
        float b2 = __shfl_xor(a2, m, 64);
        float b3 = __shfl_xor(a3, m, 64);
        // bitonic split of [a0..a3, b3..b0]: top half = top-4 of union (bitonic)
        float m0 = fmaxf(a0, b3), m1 = fmaxf(a1, b2), m2 = fmaxf(a2, b1), m3 = fmaxf(a3, b0);
        // bitonic sort-4 descending
        float e0 = fmaxf(m0, m2), e2 = fminf(m0, m2);
        float e1 = fmaxf(m1, m3), e3 = fminf(m1, m3);
        a0 = fmaxf(e0, e1); a1 = fminf(e0, e1);
        a2 = fmaxf(e2, e3); a3 = fminf(e2, e3);
    }

    if (lane == 0) {
        ((float4*)(out + OUT_X))[row] = make_float4(a0, a1, a2, a3);
    }
}

// ---------------- y: min over dim 2 of [8,32,2048,64] ----------------

__device__ __forceinline__ float4 min4(float4 a, float4 b) {
    return make_float4(fminf(a.x, b.x), fminf(a.y, b.y), fminf(a.z, b.z), fminf(a.w, b.w));
}

__global__ __launch_bounds__(1024) void ymin_kernel(const float* __restrict__ y,
                                                    float* __restrict__ out) {
    const int pair = blockIdx.x;                 // 256 (b0,b1) pairs
    const int c4 = threadIdx.x & 15;             // float4 column (16 per row of 64)
    const int rg = threadIdx.x >> 4;             // row group 0..63
    const float4* base = (const float4*)(y + (size_t)pair * 2048 * 64);

    float4 m = make_float4(3.402823466e38f, 3.402823466e38f, 3.402823466e38f, 3.402823466e38f);
    #pragma unroll 4
    for (int r = rg; r < 2048; r += 64) {
        m = min4(m, base[r * 16 + c4]);
    }

    __shared__ float4 red[1024];   // 16 KiB
    red[threadIdx.x] = m;
    __syncthreads();
    #pragma unroll
    for (int s = 512; s >= 16; s >>= 1) {
        if (threadIdx.x < s) red[threadIdx.x] = min4(red[threadIdx.x], red[threadIdx.x + s]);
        __syncthreads();
    }
    if (threadIdx.x < 16) {
        ((float4*)(out + OUT_Y + pair * 64))[threadIdx.x] = red[threadIdx.x];
    }
}

// ---------------- z: top-3 values+indices over rows of 512 ----------------
// Key: (monotone uint of float) << 32 | (511 - idx). max-order == (value desc, idx asc),
// exactly jax.lax.top_k tie semantics.

__device__ __forceinline__ unsigned long long mkkey(float v, int idx) {
    unsigned int b = __float_as_uint(v);
    unsigned int u = b ^ ((unsigned int)((int)b >> 31) | 0x80000000u);
    return ((unsigned long long)u << 32) | (unsigned int)(511 - idx);
}

__device__ __forceinline__ void ins3(unsigned long long &k0, unsigned long long &k1,
                                     unsigned long long &k2, unsigned long long k) {
    unsigned long long t;
    t = (k0 > k) ? k : k0; k0 = (k0 > k) ? k0 : k; k = t;
    t = (k1 > k) ? k : k1; k1 = (k1 > k) ? k1 : k; k = t;
    k2 = (k2 > k) ? k2 : k;
}

__device__ __forceinline__ void ce64(unsigned long long &a, unsigned long long &b) {
    unsigned long long hi = (a > b) ? a : b;
    unsigned long long lo = (a > b) ? b : a;
    a = hi; b = lo;
}

__device__ __forceinline__ unsigned long long shfl_xor_u64(unsigned long long v, int mask) {
    unsigned int lo = (unsigned int)v;
    unsigned int hi = (unsigned int)(v >> 32);
    lo = __shfl_xor(lo, mask, 64);
    hi = __shfl_xor(hi, mask, 64);
    return ((unsigned long long)hi << 32) | lo;
}

__global__ __launch_bounds__(256) void topk_z_kernel(const float* __restrict__ z,
                                                     float* __restrict__ outv,
                                                     float* __restrict__ outi) {
    const int lane = threadIdx.x & 63;
    const int row  = blockIdx.x * 4 + (threadIdx.x >> 6);   // 131072 rows
    const float4* r4 = (const float4*)(z + (size_t)row * 512);

    unsigned long long k0 = 0ull, k1 = 0ull, k2 = 0ull;
    #pragma unroll
    for (int c = 0; c < 2; ++c) {
        int i = lane + 64 * c;
        float4 v = r4[i];
        int base = 4 * i;
        ins3(k0, k1, k2, mkkey(v.x, base));
        ins3(k0, k1, k2, mkkey(v.y, base + 1));
        ins3(k0, k1, k2, mkkey(v.z, base + 2));
        ins3(k0, k1, k2, mkkey(v.w, base + 3));
    }

    #pragma unroll
    for (int m = 1; m < 64; m <<= 1) {
        unsigned long long b0 = shfl_xor_u64(k0, m);
        unsigned long long b1 = shfl_xor_u64(k1, m);
        unsigned long long b2 = shfl_xor_u64(k2, m);
        // bitonic split of [k0,k1,k2,b2,b1,b0]: top half holds top-3 of union
        unsigned long long m0 = (k0 > b2) ? k0 : b2;
        unsigned long long m1 = (k1 > b1) ? k1 : b1;
        unsigned long long m2 = (k2 > b0) ? k2 : b0;
        ce64(m0, m1); ce64(m1, m2); ce64(m0, m1);   // sort-3 descending
        k0 = m0; k1 = m1; k2 = m2;
    }

    if (lane == 0) {
        unsigned long long ks[3] = {k0, k1, k2};
        #pragma unroll
        for (int j = 0; j < 3; ++j) {
            unsigned int u = (unsigned int)(ks[j] >> 32);
            unsigned int b = (u & 0x80000000u) ? (u ^ 0x80000000u) : ~u;
            outv[(size_t)row * 3 + j] = __uint_as_float(b);
            outi[(size_t)row * 3 + j] = (float)(511 - (int)(ks[j] & 0xFFFFFFFFu));
        }
    }
}

extern "C" void kernel_launch(void* const* d_in, const int* in_sizes, int n_in,
                              void* d_out, int out_size, void* d_ws, size_t ws_size,
                              hipStream_t stream) {
    const float* x = (const float*)d_in[0];
    const float* y = (const float*)d_in[1];
    const float* z = (const float*)d_in[2];
    float* out = (float*)d_out;

    topk_x_kernel<<<65536 / 4, 256, 0, stream>>>(x, out);
    ymin_kernel<<<256, 1024, 0, stream>>>(y, out);
    topk_z_kernel<<<131072 / 4, 256, 0, stream>>>(z, out + OUT_ZV, out + OUT_ZI);
}

// Round 3
// 564.718 us; speedup vs baseline: 1.0654x; 1.0654x over previous
//
#include <hip/hip_runtime.h>

// Output layout (floats): x_top[262144] | y_min[16384] | z_val[393216] | z_idx[393216]
#define OUT_X  0
#define OUT_Y  262144
#define OUT_ZV 278528
#define OUT_ZI 671744

// Block partition: [0,256) = y, [256, 256+32768) = z, [33024, 33024+16384) = x
#define YB 256
#define ZB 32768
#define XB 16384

// native vector type for nontemporal builtin (HIP's float4 is a class)
typedef float vf4 __attribute__((ext_vector_type(4)));

__device__ __forceinline__ float4 ldnt4(const float4* p) {
    vf4 v = __builtin_nontemporal_load((const vf4*)p);
    return make_float4(v.x, v.y, v.z, v.w);
}

// ---------------- helpers: x (float top-4) ----------------

__device__ __forceinline__ void bub4(float &a0, float &a1, float &a2, float &a3, float v) {
    float r;
    r = fminf(a0, v); a0 = fmaxf(a0, v); v = r;
    r = fminf(a1, v); a1 = fmaxf(a1, v); v = r;
    r = fminf(a2, v); a2 = fmaxf(a2, v); v = r;
    a3 = fmaxf(a3, v);
}

// merge two sorted-desc 4-lists -> sorted-desc top-4 of union (bitonic)
__device__ __forceinline__ void merge4(float &a0, float &a1, float &a2, float &a3,
                                       float b0, float b1, float b2, float b3) {
    float m0 = fmaxf(a0, b3), m1 = fmaxf(a1, b2), m2 = fmaxf(a2, b1), m3 = fmaxf(a3, b0);
    float e0 = fmaxf(m0, m2), e2 = fminf(m0, m2);
    float e1 = fmaxf(m1, m3), e3 = fminf(m1, m3);
    a0 = fmaxf(e0, e1); a1 = fminf(e0, e1);
    a2 = fmaxf(e2, e3); a3 = fminf(e2, e3);
}

// ---------------- helpers: y (float4 min) ----------------

__device__ __forceinline__ float4 min4(float4 a, float4 b) {
    return make_float4(fminf(a.x, b.x), fminf(a.y, b.y), fminf(a.z, b.z), fminf(a.w, b.w));
}

// ---------------- helpers: z (u64-keyed top-3) ----------------
// Key: (monotone uint of float) << 32 | (511 - idx). max-order == (value desc, idx asc).

__device__ __forceinline__ unsigned long long mkkey(float v, int idx) {
    unsigned int b = __float_as_uint(v);
    unsigned int u = b ^ ((unsigned int)((int)b >> 31) | 0x80000000u);
    return ((unsigned long long)u << 32) | (unsigned int)(511 - idx);
}

__device__ __forceinline__ void ins3(unsigned long long &k0, unsigned long long &k1,
                                     unsigned long long &k2, unsigned long long k) {
    unsigned long long t;
    t = (k0 > k) ? k : k0; k0 = (k0 > k) ? k0 : k; k = t;
    t = (k1 > k) ? k : k1; k1 = (k1 > k) ? k1 : k; k = t;
    k2 = (k2 > k) ? k2 : k;
}

__device__ __forceinline__ void ce64(unsigned long long &a, unsigned long long &b) {
    unsigned long long hi = (a > b) ? a : b;
    unsigned long long lo = (a > b) ? b : a;
    a = hi; b = lo;
}

// merge two sorted-desc 3-lists -> sorted-desc top-3 of union (bitonic)
__device__ __forceinline__ void merge3(unsigned long long &a0, unsigned long long &a1,
                                       unsigned long long &a2,
                                       unsigned long long b0, unsigned long long b1,
                                       unsigned long long b2) {
    unsigned long long m0 = (a0 > b2) ? a0 : b2;
    unsigned long long m1 = (a1 > b1) ? a1 : b1;
    unsigned long long m2 = (a2 > b0) ? a2 : b0;
    ce64(m0, m1); ce64(m1, m2); ce64(m0, m1);
    a0 = m0; a1 = m1; a2 = m2;
}

__device__ __forceinline__ unsigned long long shfl_xor_u64(unsigned long long v, int mask) {
    unsigned int lo = (unsigned int)v;
    unsigned int hi = (unsigned int)(v >> 32);
    lo = __shfl_xor(lo, mask, 64);
    hi = __shfl_xor(hi, mask, 64);
    return ((unsigned long long)hi << 32) | lo;
}

// ---------------- fused kernel ----------------

__global__ __launch_bounds__(256) void fused_topk_kernel(const float* __restrict__ x,
                                                         const float* __restrict__ y,
                                                         const float* __restrict__ z,
                                                         float* __restrict__ out) {
    const int bid = blockIdx.x;
    const int tid = threadIdx.x;

    if (bid < YB) {
        // ---- y: min over dim 2 of [8,32,2048,64]; one block per (b0,b1) pair ----
        const int pair = bid;
        const int c4 = tid & 15;          // float4 column
        const int rg = tid >> 4;          // row group 0..15
        const float4* base = (const float4*)(y + (size_t)pair * 2048 * 64);

        const float INF = 3.402823466e38f;
        float4 m = make_float4(INF, INF, INF, INF);
        #pragma unroll 8
        for (int r = rg; r < 2048; r += 16) {
            m = min4(m, ldnt4(base + r * 16 + c4));
        }

        __shared__ float4 red[256];       // 4 KiB
        red[tid] = m;
        __syncthreads();
        #pragma unroll
        for (int s = 128; s >= 16; s >>= 1) {
            if (tid < s) red[tid] = min4(red[tid], red[tid + s]);
            __syncthreads();
        }
        if (tid < 16) {
            ((float4*)(out + OUT_Y + pair * 64))[tid] = red[tid];
        }
    } else if (bid < YB + ZB) {
        // ---- z: top-3 vals+idx over rows of 512; one wave per row ----
        const int lane = tid & 63;
        const int row  = (bid - YB) * 4 + (tid >> 6);
        const float4* r4 = (const float4*)(z + (size_t)row * 512);

        float4 v0 = ldnt4(r4 + lane);
        float4 v1 = ldnt4(r4 + lane + 64);

        // two independent chains, merged once (halves dep-chain latency)
        unsigned long long a0 = 0ull, a1 = 0ull, a2 = 0ull;
        unsigned long long b0 = 0ull, b1 = 0ull, b2 = 0ull;
        int i0 = 4 * lane, i1 = 4 * (lane + 64);
        ins3(a0, a1, a2, mkkey(v0.x, i0));
        ins3(b0, b1, b2, mkkey(v1.x, i1));
        ins3(a0, a1, a2, mkkey(v0.y, i0 + 1));
        ins3(b0, b1, b2, mkkey(v1.y, i1 + 1));
        ins3(a0, a1, a2, mkkey(v0.z, i0 + 2));
        ins3(b0, b1, b2, mkkey(v1.z, i1 + 2));
        ins3(a0, a1, a2, mkkey(v0.w, i0 + 3));
        ins3(b0, b1, b2, mkkey(v1.w, i1 + 3));
        merge3(a0, a1, a2, b0, b1, b2);

        #pragma unroll
        for (int m = 1; m < 64; m <<= 1) {
            unsigned long long s0 = shfl_xor_u64(a0, m);
            unsigned long long s1 = shfl_xor_u64(a1, m);
            unsigned long long s2 = shfl_xor_u64(a2, m);
            merge3(a0, a1, a2, s0, s1, s2);
        }

        if (lane == 0) {
            unsigned long long ks[3] = {a0, a1, a2};
            float* outv = out + OUT_ZV;
            float* outi = out + OUT_ZI;
            #pragma unroll
            for (int j = 0; j < 3; ++j) {
                unsigned int u = (unsigned int)(ks[j] >> 32);
                unsigned int bb = (u & 0x80000000u) ? (u ^ 0x80000000u) : ~u;
                outv[(size_t)row * 3 + j] = __uint_as_float(bb);
                outi[(size_t)row * 3 + j] = (float)(511 - (int)(ks[j] & 0xFFFFFFFFu));
            }
        }
    } else {
        // ---- x: top-4 over rows of 1024; one wave per row ----
        const int lane = tid & 63;
        const int row  = (bid - YB - ZB) * 4 + (tid >> 6);
        const float4* r4 = (const float4*)(x + (size_t)row * 1024);

        float4 v0 = ldnt4(r4 + lane);
        float4 v1 = ldnt4(r4 + lane + 64);
        float4 v2 = ldnt4(r4 + lane + 128);
        float4 v3 = ldnt4(r4 + lane + 192);

        const float NINF = -3.402823466e38f;
        // two independent chains, merged once
        float a0 = NINF, a1 = NINF, a2 = NINF, a3 = NINF;
        float c0 = NINF, c1 = NINF, c2 = NINF, c3 = NINF;
        bub4(a0, a1, a2, a3, v0.x); bub4(c0, c1, c2, c3, v2.x);
        bub4(a0, a1, a2, a3, v0.y); bub4(c0, c1, c2, c3, v2.y);
        bub4(a0, a1, a2, a3, v0.z); bub4(c0, c1, c2, c3, v2.z);
        bub4(a0, a1, a2, a3, v0.w); bub4(c0, c1, c2, c3, v2.w);
        bub4(a0, a1, a2, a3, v1.x); bub4(c0, c1, c2, c3, v3.x);
        bub4(a0, a1, a2, a3, v1.y); bub4(c0, c1, c2, c3, v3.y);
        bub4(a0, a1, a2, a3, v1.z); bub4(c0, c1, c2, c3, v3.z);
        bub4(a0, a1, a2, a3, v1.w); bub4(c0, c1, c2, c3, v3.w);
        merge4(a0, a1, a2, a3, c0, c1, c2, c3);

        #pragma unroll
        for (int m = 1; m < 64; m <<= 1) {
            float s0 = __shfl_xor(a0, m, 64);
            float s1 = __shfl_xor(a1, m, 64);
            float s2 = __shfl_xor(a2, m, 64);
            float s3 = __shfl_xor(a3, m, 64);
            merge4(a0, a1, a2, a3, s0, s1, s2, s3);
        }

        if (lane == 0) {
            ((float4*)(out + OUT_X))[row] = make_float4(a0, a1, a2, a3);
        }
    }
}

extern "C" void kernel_launch(void* const* d_in, const int* in_sizes, int n_in,
                              void* d_out, int out_size, void* d_ws, size_t ws_size,
                              hipStream_t stream) {
    const float* x = (const float*)d_in[0];
    const float* y = (const float*)d_in[1];
    const float* z = (const float*)d_in[2];
    float* out = (float*)d_out;

    fused_topk_kernel<<<YB + ZB + XB, 256, 0, stream>>>(x, y, z, out);
}